// Round 2
// baseline (1167.146 us; speedup 1.0000x reference)
//
#include <hip/hip_runtime.h>

// Problem constants: B=16, N=4096, C=256, WS=8, NH=8, HD=32, LK=32, G=16
// Windows: 1024 blocks of 64 tokens. All inputs/outputs are FP32 (reference
// dtypes). x, E_k, E_v are staged in LDS as bf16 (round-trip error ~0.2%,
// threshold is 2.6e-3 on |out|max 0.13 — ample margin). All arithmetic fp32.

typedef unsigned int uint;

__device__ __forceinline__ float bup(unsigned short hs) {
    return __uint_as_float(((uint)hs) << 16);
}
__device__ __forceinline__ uint f2b(float f) {   // fp32 -> bf16 bits (RNE)
    uint u = __float_as_uint(f);
    return (u + 0x7FFFu + ((u >> 16) & 1u)) >> 16;
}

// ---- LDS carve (bytes), total 157568 (<160 KiB, proven launchable R1) ----
// x_su   : bf16 [64][256]   @ 0       (32768)
// attn_s : f32  [64][257]   @ 32768   (65792)
// q_s    : f32  [64][33]    @ 98560   (8448)
// k_s    : f32  [64][33]    @ 107008  (8448)
// v_s    : f32  [64][33]    @ 115456  (8448)
// kfull  : f32  [48][33]    @ 123904  (6336)
// vfull  : f32  [48][33]    @ 130240  (6336)
// scores : f32  [64][49]    @ 136576  (12544)
// Ek_su  : bf16 [64][32]    @ 149120  (4096)
// Ev_su  : bf16 [64][32]    @ 153216  (4096)
// row_inv: f32  [64]        @ 157312  (256)
#define SMEM_BYTES 157568

extern "C" __global__ void __launch_bounds__(512)
eswa_fused(const float* __restrict__ x, const float* __restrict__ Wqkv,
           const float* __restrict__ bqkv, const float* __restrict__ Ek,
           const float* __restrict__ Ev, const float* __restrict__ kbank,
           const float* __restrict__ vbank, const float* __restrict__ Wproj,
           const float* __restrict__ bproj, float* __restrict__ out)
{
    extern __shared__ char smem[];
    unsigned short* x_su  = (unsigned short*)smem;
    float* attn_s  = (float*)(smem + 32768);
    float* q_s     = (float*)(smem + 98560);
    float* k_s     = (float*)(smem + 107008);
    float* v_s     = (float*)(smem + 115456);
    float* kfull   = (float*)(smem + 123904);
    float* vfull   = (float*)(smem + 130240);
    float* scores  = (float*)(smem + 136576);
    unsigned short* Ek_su = (unsigned short*)(smem + 149120);
    unsigned short* Ev_su = (unsigned short*)(smem + 153216);
    float* row_inv = (float*)(smem + 157312);

    const int tid = threadIdx.x;
    const int b   = blockIdx.x >> 6;
    const int w   = blockIdx.x & 63;
    const int rw  = w >> 3;
    const int cw  = w & 7;

    // ---- stage x window: fp32 global -> bf16 LDS, row-major [t][256] ----
    // 4096 float4 chunks; lanes along channels => coalesced 1KB/instr;
    // LDS write bank = 2*lane % 32 => 2-way (free).
    #pragma unroll
    for (int i = 0; i < 8; ++i) {
        int vi = tid + 512 * i;          // 0..4095
        int t  = vi >> 6;                // token 0..63
        int c  = (vi & 63) * 4;          // channel
        int n  = (rw * 8 + (t >> 3)) * 64 + cw * 8 + (t & 7);
        const float4 xv = *(const float4*)(x + (size_t)(b * 4096 + n) * 256 + c);
        uint lo = f2b(xv.x) | (f2b(xv.y) << 16);
        uint hi = f2b(xv.z) | (f2b(xv.w) << 16);
        *(uint2*)(x_su + t * 256 + c) = make_uint2(lo, hi);
    }
    // ---- stage E_k / E_v: 2048 floats each, 4 per thread ----
    {
        const float4 e1 = *(const float4*)(Ek + tid * 4);
        const float4 e2 = *(const float4*)(Ev + tid * 4);
        *(uint2*)(Ek_su + tid * 4) =
            make_uint2(f2b(e1.x) | (f2b(e1.y) << 16), f2b(e1.z) | (f2b(e1.w) << 16));
        *(uint2*)(Ev_su + tid * 4) =
            make_uint2(f2b(e2.x) | (f2b(e2.y) << 16), f2b(e2.z) | (f2b(e2.w) << 16));
    }
    __syncthreads();

    const int d  = tid & 31;     // head-dim index
    const int g  = tid >> 5;     // 0..15
    const int t0 = g * 4;        // 4 tokens per thread in QKV phase

    for (int h = 0; h < 8; ++h) {
        // ---- QKV projection: thread (g,d) -> q/k/v[t0..t0+3][h*32+d] ----
        {
            const float bq = bqkv[h * 32 + d];
            const float bk = bqkv[256 + h * 32 + d];
            const float bv = bqkv[512 + h * 32 + d];
            float aq[4], ak[4], av[4];
            #pragma unroll
            for (int i = 0; i < 4; ++i) { aq[i] = bq; ak[i] = bk; av[i] = bv; }
            const float* wqp = Wqkv + h * 32 + d;

            for (int rb = 0; rb < 32; ++rb) {
                uint4 xr[4];
                #pragma unroll
                for (int i = 0; i < 4; ++i)    // ds_read_b128, conflict-free
                    xr[i] = *(const uint4*)(x_su + (t0 + i) * 256 + rb * 8);
                #pragma unroll
                for (int j = 0; j < 8; ++j) {
                    const int r = rb * 8 + j;
                    const float wq = wqp[(size_t)r * 768];
                    const float wk = wqp[(size_t)r * 768 + 256];
                    const float wv = wqp[(size_t)r * 768 + 512];
                    #pragma unroll
                    for (int i = 0; i < 4; ++i) {
                        const uint u = ((const uint*)&xr[i])[j >> 1];
                        const float xf = (j & 1) ? __uint_as_float(u & 0xFFFF0000u)
                                                 : __uint_as_float(u << 16);
                        aq[i] = fmaf(xf, wq, aq[i]);
                        ak[i] = fmaf(xf, wk, ak[i]);
                        av[i] = fmaf(xf, wv, av[i]);
                    }
                }
            }
            #pragma unroll
            for (int i = 0; i < 4; ++i) {
                q_s[(t0 + i) * 33 + d] = aq[i];
                k_s[(t0 + i) * 33 + d] = ak[i];
                v_s[(t0 + i) * 33 + d] = av[i];
            }
        }
        __syncthreads();

        // ---- Linformer compression (rows 0..31) + bank rows (32..47) ----
        {
            #pragma unroll
            for (int j = 0; j < 2; ++j) {
                const int kk = g + 16 * j;
                float aK = 0.f, aV = 0.f;
                #pragma unroll 4
                for (int t = 0; t < 64; ++t) {
                    aK = fmaf(bup(Ek_su[t * 32 + kk]), k_s[t * 33 + d], aK);
                    aV = fmaf(bup(Ev_su[t * 32 + kk]), v_s[t * 33 + d], aV);
                }
                kfull[kk * 33 + d] = aK;
                vfull[kk * 33 + d] = aV;
            }
            // bank rows: 512 entries, one per thread
            kfull[(32 + g) * 33 + d] = kbank[g * 256 + h * 32 + d];
            vfull[(32 + g) * 33 + d] = vbank[g * 256 + h * 32 + d];
        }
        __syncthreads();

        // ---- scores[64][48] = q @ kfull^T * scale ----
        {
            const int t = tid >> 3, jg = tid & 7;
            #pragma unroll
            for (int jj = 0; jj < 6; ++jj) {
                const int j = jg * 6 + jj;
                float s = 0.f;
                #pragma unroll
                for (int dd = 0; dd < 32; ++dd)
                    s = fmaf(q_s[t * 33 + dd], kfull[j * 33 + dd], s);
                scores[t * 49 + j] = s * 0.17677669529663687f;  // 1/sqrt(32)
            }
        }
        __syncthreads();

        // ---- softmax, one thread per row ----
        if (tid < 64) {
            const int t = tid;
            float m = -1e30f;
            #pragma unroll
            for (int j = 0; j < 48; ++j) m = fmaxf(m, scores[t * 49 + j]);
            float s = 0.f;
            #pragma unroll
            for (int j = 0; j < 48; ++j) {
                const float e = __expf(scores[t * 49 + j] - m);
                scores[t * 49 + j] = e;
                s += e;
            }
            row_inv[t] = 1.0f / s;
        }
        __syncthreads();

        // ---- out_h = softmax(scores) @ vfull -> attn_s[:, h*32..h*32+31] ----
        {
            const int t = tid >> 3, dg = tid & 7;
            #pragma unroll
            for (int ii = 0; ii < 4; ++ii) {
                const int dd = dg * 4 + ii;
                float a = 0.f;
                #pragma unroll
                for (int j = 0; j < 48; ++j)
                    a = fmaf(scores[t * 49 + j], vfull[j * 33 + dd], a);
                attn_s[t * 257 + h * 32 + dd] = a * row_inv[t];
            }
        }
        __syncthreads();
    }

    // ---- output projection: out[64][256] = attn_s @ Wproj + bproj ----
    // thread (tt=tid>>6, ct=tid&63): tokens tt*8..+7, channels ct*4..+3
    {
        const int tt = tid >> 6;
        const int ct = tid & 63;
        float acc[8][4];
        #pragma unroll
        for (int i = 0; i < 8; ++i)
            #pragma unroll
            for (int j = 0; j < 4; ++j) acc[i][j] = 0.f;

        const float* wpp = Wproj + ct * 4;
        #pragma unroll 2
        for (int r = 0; r < 256; ++r) {
            const float4 wv4 = *(const float4*)(wpp + (size_t)r * 256);
            float a[8];
            #pragma unroll
            for (int i = 0; i < 8; ++i) a[i] = attn_s[(tt * 8 + i) * 257 + r];
            #pragma unroll
            for (int i = 0; i < 8; ++i) {
                acc[i][0] = fmaf(a[i], wv4.x, acc[i][0]);
                acc[i][1] = fmaf(a[i], wv4.y, acc[i][1]);
                acc[i][2] = fmaf(a[i], wv4.z, acc[i][2]);
                acc[i][3] = fmaf(a[i], wv4.w, acc[i][3]);
            }
        }

        const float4 bp = *(const float4*)(bproj + ct * 4);
        #pragma unroll
        for (int i = 0; i < 8; ++i) {
            const int t = tt * 8 + i;
            const int n = (rw * 8 + (t >> 3)) * 64 + cw * 8 + (t & 7);
            float4 o;
            o.x = acc[i][0] + bp.x;
            o.y = acc[i][1] + bp.y;
            o.z = acc[i][2] + bp.z;
            o.w = acc[i][3] + bp.w;
            *(float4*)(out + (size_t)(b * 4096 + n) * 256 + ct * 4) = o;
        }
    }
}

extern "C" void kernel_launch(void* const* d_in, const int* in_sizes, int n_in,
                              void* d_out, int out_size, void* d_ws, size_t ws_size,
                              hipStream_t stream) {
    const float* x     = (const float*)d_in[0];
    const float* Wqkv  = (const float*)d_in[1];
    const float* bqkv  = (const float*)d_in[2];
    const float* Ek    = (const float*)d_in[3];
    const float* Ev    = (const float*)d_in[4];
    const float* kbank = (const float*)d_in[5];
    const float* vbank = (const float*)d_in[6];
    const float* Wproj = (const float*)d_in[7];
    const float* bproj = (const float*)d_in[8];
    float* outp        = (float*)d_out;
    (void)in_sizes; (void)n_in; (void)out_size; (void)d_ws; (void)ws_size;

    // host-side attribute set; idempotent, graph-capture safe
    hipFuncSetAttribute((const void*)eswa_fused,
                        hipFuncAttributeMaxDynamicSharedMemorySize, SMEM_BYTES);

    eswa_fused<<<1024, 512, SMEM_BYTES, stream>>>(x, Wqkv, bqkv, Ek, Ev,
                                                  kbank, vbank, Wproj, bproj, outp);
}

// Round 3
// 492.253 us; speedup vs baseline: 2.3710x; 2.3710x over previous
//
#include <hip/hip_runtime.h>

// B=16, N=4096, C=256, WS=8 -> 1024 windows x 64 tokens; NH=8, HD=32, LK=32, G=16.
// All inputs/outputs fp32. GEMMs on MFMA 16x16x32 bf16.
// prep kernel: split Wqkv/Wproj into bf16 hi+lo, packed in B-fragment lane order;
// Ek/Ev transposed + packed in A-fragment order. Stored in d_ws.
// Main kernel: 1 block = 1 window, 512 threads (8 waves).
//   QKV: bf16x3 (xh@Wh + xh@Wl + xl@Wh)  -> x,W effectively fp32-exact
//   proj: attn_bf16 @ (Wh + Wl)
//   attention pipeline fully MFMA; softmax fp32 on 512 threads.

typedef unsigned int uint;
typedef __attribute__((ext_vector_type(8))) short short8;   // 8 x bf16 (4 VGPRs)
typedef __attribute__((ext_vector_type(4))) float f32x4;

__device__ __forceinline__ float bup(unsigned short hs) {
    return __uint_as_float(((uint)hs) << 16);
}
__device__ __forceinline__ uint f2b(float f) {   // fp32 -> bf16 bits (RNE)
    uint u = __float_as_uint(f);
    return (u + 0x7FFFu + ((u >> 16) & 1u)) >> 16;
}
__device__ __forceinline__ f32x4 mfma16(short8 a, short8 b, f32x4 c) {
    return __builtin_amdgcn_mfma_f32_16x16x32_bf16(a, b, c, 0, 0, 0);
}

// ---- workspace layout (shorts) ----
// Wh_qkv @ 0        [48 tn][8 tk][64 lane][8]   = 196608
// Wl_qkv @ 196608                               = 196608
// Wh_prj @ 393216   [16 tn][8 tk][64 lane][8]   = 65536
// Wl_prj @ 458752                               = 65536
// EkT    @ 524288   [2 tm][2 tk][64 lane][8]    = 2048
// EvT    @ 526336                               = 2048
// total 528384 shorts = 1056768 bytes
#define WS_WHQ 0
#define WS_WLQ 196608
#define WS_WHP 393216
#define WS_WLP 458752
#define WS_EKT 524288
#define WS_EVT 526336

__global__ void __launch_bounds__(256)
eswa_prep(const float* __restrict__ Wqkv, const float* __restrict__ Wproj,
          const float* __restrict__ Ek, const float* __restrict__ Ev,
          short* __restrict__ wsp)
{
    const int id = blockIdx.x * 256 + threadIdx.x;   // grid covers 266240
    if (id < 196608) {
        const int j = id & 7, ln = (id >> 3) & 63, tk = (id >> 9) & 7, tn = id >> 12;
        const int r = tk * 32 + (ln >> 4) * 8 + j;
        const int c = tn * 16 + (ln & 15);
        const float w = Wqkv[r * 768 + c];
        const unsigned short hi = (unsigned short)f2b(w);
        wsp[WS_WHQ + id] = (short)hi;
        wsp[WS_WLQ + id] = (short)f2b(w - bup(hi));
    } else if (id < 262144) {
        const int q = id - 196608;
        const int j = q & 7, ln = (q >> 3) & 63, tk = (q >> 9) & 7, tn = q >> 12;
        const int r = tk * 32 + (ln >> 4) * 8 + j;
        const int c = tn * 16 + (ln & 15);
        const float w = Wproj[r * 256 + c];
        const unsigned short hi = (unsigned short)f2b(w);
        wsp[WS_WHP + q] = (short)hi;
        wsp[WS_WLP + q] = (short)f2b(w - bup(hi));
    } else if (id < 264192) {
        const int e = id - 262144;
        const int j = e & 7, ln = (e >> 3) & 63, tk = (e >> 9) & 1, tm = e >> 10;
        const int t = tk * 32 + (ln >> 4) * 8 + j;
        const int lk = tm * 16 + (ln & 15);
        wsp[WS_EKT + e] = (short)f2b(Ek[t * 32 + lk]);
    } else if (id < 266240) {
        const int e = id - 264192;
        const int j = e & 7, ln = (e >> 3) & 63, tk = (e >> 9) & 1, tm = e >> 10;
        const int t = tk * 32 + (ln >> 4) * 8 + j;
        const int lk = tm * 16 + (ln & 15);
        wsp[WS_EVT + e] = (short)f2b(Ev[t * 32 + lk]);
    }
}

// ---- LDS layout (bytes) ----
// xh     bf16 [64][264] @ 0        33792
// xl     bf16 [64][264] @ 33792    33792
// attn   bf16 [64][264] @ 67584    33792
// qs     bf16 [64][40]  @ 101376   5120
// kT     bf16 [32][72]  @ 106496   4608
// vT     bf16 [32][72]  @ 111104   4608
// kfull  bf16 [48][40]  @ 115712   3840
// vfullT bf16 [32][72]  @ 119552   4608
// scores f32  [64][52]  @ 124160   13312
// p_s    bf16 [64][72]  @ 137472   9216   -> total 146688
#define SMEM_BYTES 146688

__global__ void __launch_bounds__(512)
eswa_main(const float* __restrict__ x, const float* __restrict__ bqkv,
          const float* __restrict__ kbank, const float* __restrict__ vbank,
          const float* __restrict__ bproj, const short* __restrict__ wsp,
          float* __restrict__ out)
{
    extern __shared__ char smem[];
    short* xh     = (short*)(smem);
    short* xl     = (short*)(smem + 33792);
    short* attn   = (short*)(smem + 67584);
    short* qs     = (short*)(smem + 101376);
    short* kT     = (short*)(smem + 106496);
    short* vT     = (short*)(smem + 111104);
    short* kfull  = (short*)(smem + 115712);
    short* vfullT = (short*)(smem + 119552);
    float* scores = (float*)(smem + 124160);
    short* p_s    = (short*)(smem + 137472);

    const int tid  = threadIdx.x;
    const int wave = tid >> 6;
    const int lane = tid & 63;
    const int quad = lane >> 4;
    const int l16  = lane & 15;

    const int b  = blockIdx.x >> 6;
    const int w  = blockIdx.x & 63;
    const int rw = w >> 3;
    const int cw = w & 7;

    // ---- stage x -> xh/xl (bf16 hi/lo), row-major [token][264] ----
    #pragma unroll
    for (int i = 0; i < 8; ++i) {
        const int vi = tid + 512 * i;          // 0..4095
        const int t  = vi >> 6;
        const int c  = (vi & 63) * 4;
        const int n  = (rw * 8 + (t >> 3)) * 64 + cw * 8 + (t & 7);
        const float4 xv = *(const float4*)(x + (size_t)(b * 4096 + n) * 256 + c);
        uint h0 = f2b(xv.x), h1 = f2b(xv.y), h2 = f2b(xv.z), h3 = f2b(xv.w);
        uint l0 = f2b(xv.x - bup((unsigned short)h0));
        uint l1 = f2b(xv.y - bup((unsigned short)h1));
        uint l2 = f2b(xv.z - bup((unsigned short)h2));
        uint l3 = f2b(xv.w - bup((unsigned short)h3));
        *(uint2*)(xh + t * 264 + c) = make_uint2(h0 | (h1 << 16), h2 | (h3 << 16));
        *(uint2*)(xl + t * 264 + c) = make_uint2(l0 | (l1 << 16), l2 | (l3 << 16));
    }
    // zero pads used by PV K-padding (written once, never overwritten)
    for (int i = tid; i < 768; i += 512) {            // vfullT cols 48..71
        const int d = i / 24, c = 48 + i % 24;
        vfullT[d * 72 + c] = 0;
    }
    for (int i = tid; i < 1536; i += 512) {           // p_s cols 48..71
        const int r = i / 24, c = 48 + i % 24;
        p_s[r * 72 + c] = 0;
    }
    __syncthreads();

    const short* Whq = wsp + WS_WHQ;
    const short* Wlq = wsp + WS_WLQ;

    #pragma unroll 1
    for (int h = 0; h < 8; ++h) {
        // ================= phase 1: QKV MFMA (bf16x3) =================
        {
            const int m0 = (wave >> 1) * 16;
            const int nh = wave & 1;
            int tn0, tn1, tn2, sec0, sec1, sec2, d00, d01, d02;
            if (nh == 0) { tn0 = 2*h;    tn1 = 2*h+1;  tn2 = 16+2*h;
                           sec0 = 0; sec1 = 0; sec2 = 1; d00 = 0; d01 = 16; d02 = 0; }
            else         { tn0 = 17+2*h; tn1 = 32+2*h; tn2 = 33+2*h;
                           sec0 = 1; sec1 = 2; sec2 = 2; d00 = 16; d01 = 0; d02 = 16; }
            f32x4 acc0, acc1, acc2;
            {
                const float b0 = bqkv[sec0 * 256 + h * 32 + d00 + l16];
                const float b1 = bqkv[sec1 * 256 + h * 32 + d01 + l16];
                const float b2 = bqkv[sec2 * 256 + h * 32 + d02 + l16];
                acc0 = (f32x4){b0, b0, b0, b0};
                acc1 = (f32x4){b1, b1, b1, b1};
                acc2 = (f32x4){b2, b2, b2, b2};
            }
            #pragma unroll 2
            for (int tk = 0; tk < 8; ++tk) {
                const short8 ah = *(const short8*)(xh + (m0 + l16) * 264 + tk * 32 + quad * 8);
                const short8 al = *(const short8*)(xl + (m0 + l16) * 264 + tk * 32 + quad * 8);
                const int bo0 = ((tn0 * 8 + tk) * 64 + lane) * 8;
                const int bo1 = ((tn1 * 8 + tk) * 64 + lane) * 8;
                const int bo2 = ((tn2 * 8 + tk) * 64 + lane) * 8;
                const short8 bh0 = *(const short8*)(Whq + bo0);
                const short8 bl0 = *(const short8*)(Wlq + bo0);
                const short8 bh1 = *(const short8*)(Whq + bo1);
                const short8 bl1 = *(const short8*)(Wlq + bo1);
                const short8 bh2 = *(const short8*)(Whq + bo2);
                const short8 bl2 = *(const short8*)(Wlq + bo2);
                acc0 = mfma16(ah, bh0, acc0); acc0 = mfma16(ah, bl0, acc0); acc0 = mfma16(al, bh0, acc0);
                acc1 = mfma16(ah, bh1, acc1); acc1 = mfma16(ah, bl1, acc1); acc1 = mfma16(al, bh1, acc1);
                acc2 = mfma16(ah, bh2, acc2); acc2 = mfma16(ah, bl2, acc2); acc2 = mfma16(al, bh2, acc2);
            }
            // epilogue: q -> qs[t][d], k -> kT[d][t], v -> vT[d][t]
            #pragma unroll
            for (int r = 0; r < 4; ++r) {
                const int t = m0 + quad * 4 + r;
                if (sec0 == 0) qs[t * 40 + d00 + l16] = (short)f2b(acc0[r]);
                else           kT[(d00 + l16) * 72 + t] = (short)f2b(acc0[r]);
                if (sec1 == 0) qs[t * 40 + d01 + l16] = (short)f2b(acc1[r]);
                else if (sec1 == 1) kT[(d01 + l16) * 72 + t] = (short)f2b(acc1[r]);
                else           vT[(d01 + l16) * 72 + t] = (short)f2b(acc1[r]);
                if (sec2 == 1) kT[(d02 + l16) * 72 + t] = (short)f2b(acc2[r]);
                else           vT[(d02 + l16) * 72 + t] = (short)f2b(acc2[r]);
            }
        }
        __syncthreads();   // A

        // ====== phase 2: Linformer compression MFMA + bank fill ======
        {
            const int mat = wave >> 2, tm = (wave >> 1) & 1, tnc = wave & 1;
            const short* Apk  = wsp + (mat ? WS_EVT : WS_EKT);
            const short* Bsrc = mat ? vT : kT;
            f32x4 acc = (f32x4){0.f, 0.f, 0.f, 0.f};
            #pragma unroll
            for (int tk = 0; tk < 2; ++tk) {
                const short8 a = *(const short8*)(Apk + ((tm * 2 + tk) * 64 + lane) * 8);
                const short8 bf = *(const short8*)(Bsrc + (tnc * 16 + l16) * 72 + tk * 32 + quad * 8);
                acc = mfma16(a, bf, acc);
            }
            #pragma unroll
            for (int r = 0; r < 4; ++r) {
                const int lk = tm * 16 + quad * 4 + r;
                const int d  = tnc * 16 + l16;
                if (mat == 0) kfull[lk * 40 + d] = (short)f2b(acc[r]);
                else          vfullT[d * 72 + lk] = (short)f2b(acc[r]);
            }
            // bank rows 32..47 (512 entries, one per thread)
            const int g = tid >> 5, d = tid & 31;
            kfull[(32 + g) * 40 + d] = (short)f2b(kbank[g * 256 + h * 32 + d]);
            vfullT[d * 72 + 32 + g]  = (short)f2b(vbank[g * 256 + h * 32 + d]);
        }
        __syncthreads();   // B

        // ================= phase 3: scores MFMA =================
        for (int j = wave; j < 12; j += 8) {
            const int m = j / 3, n = j % 3;
            const short8 a  = *(const short8*)(qs + (m * 16 + l16) * 40 + quad * 8);
            const short8 bf = *(const short8*)(kfull + (n * 16 + l16) * 40 + quad * 8);
            f32x4 acc = (f32x4){0.f, 0.f, 0.f, 0.f};
            acc = mfma16(a, bf, acc);
            #pragma unroll
            for (int r = 0; r < 4; ++r)
                scores[(m * 16 + quad * 4 + r) * 52 + n * 16 + l16] =
                    acc[r] * 0.17677669529663687f;   // 1/sqrt(32)
        }
        __syncthreads();   // C

        // ================= phase 4: softmax (fp32) =================
        {
            const int r = tid >> 3, sub = tid & 7;
            float s[6];
            #pragma unroll
            for (int i = 0; i < 6; ++i) s[i] = scores[r * 52 + sub * 6 + i];
            float mx = s[0];
            #pragma unroll
            for (int i = 1; i < 6; ++i) mx = fmaxf(mx, s[i]);
            mx = fmaxf(mx, __shfl_xor(mx, 1));
            mx = fmaxf(mx, __shfl_xor(mx, 2));
            mx = fmaxf(mx, __shfl_xor(mx, 4));
            float e[6], sum = 0.f;
            #pragma unroll
            for (int i = 0; i < 6; ++i) { e[i] = __expf(s[i] - mx); sum += e[i]; }
            sum += __shfl_xor(sum, 1);
            sum += __shfl_xor(sum, 2);
            sum += __shfl_xor(sum, 4);
            const float inv = 1.0f / sum;
            #pragma unroll
            for (int i = 0; i < 6; ++i)
                p_s[r * 72 + sub * 6 + i] = (short)f2b(e[i] * inv);
        }
        __syncthreads();   // D

        // ================= phase 5: PV MFMA -> attn columns =================
        {
            const int m = wave >> 1, n = wave & 1;
            f32x4 acc = (f32x4){0.f, 0.f, 0.f, 0.f};
            #pragma unroll
            for (int tk = 0; tk < 2; ++tk) {
                const short8 a  = *(const short8*)(p_s + (m * 16 + l16) * 72 + tk * 32 + quad * 8);
                const short8 bf = *(const short8*)(vfullT + (n * 16 + l16) * 72 + tk * 32 + quad * 8);
                acc = mfma16(a, bf, acc);
            }
            #pragma unroll
            for (int r = 0; r < 4; ++r) {
                const int t = m * 16 + quad * 4 + r;
                attn[t * 264 + h * 32 + n * 16 + l16] = (short)f2b(acc[r]);
            }
        }
        // no barrier needed: next phase-1 doesn't touch p_s/vfullT/attn,
        // and barrier A separates next phase-2's vfullT writes from these reads.
    }
    __syncthreads();

    // ================= output projection MFMA =================
    {
        const short* Whp = wsp + WS_WHP;
        const short* Wlp = wsp + WS_WLP;
        const int m0 = (wave & 3) * 16;
        const int nb = (wave >> 2) * 8;          // 8 N-tiles per wave
        f32x4 acc[8];
        #pragma unroll
        for (int i = 0; i < 8; ++i) {
            const float bi = bproj[(nb + i) * 16 + l16];
            acc[i] = (f32x4){bi, bi, bi, bi};
        }
        #pragma unroll 2
        for (int tk = 0; tk < 8; ++tk) {
            const short8 a = *(const short8*)(attn + (m0 + l16) * 264 + tk * 32 + quad * 8);
            #pragma unroll
            for (int i = 0; i < 8; ++i) {
                const int bo = (((nb + i) * 8 + tk) * 64 + lane) * 8;
                const short8 bh = *(const short8*)(Whp + bo);
                const short8 bl = *(const short8*)(Wlp + bo);
                acc[i] = mfma16(a, bh, acc[i]);
                acc[i] = mfma16(a, bl, acc[i]);
            }
        }
        #pragma unroll
        for (int i = 0; i < 8; ++i) {
            #pragma unroll
            for (int r = 0; r < 4; ++r) {
                const int t = m0 + quad * 4 + r;
                const int n = (rw * 8 + (t >> 3)) * 64 + cw * 8 + (t & 7);
                out[(size_t)(b * 4096 + n) * 256 + (nb + i) * 16 + l16] = acc[i][r];
            }
        }
    }
}

extern "C" void kernel_launch(void* const* d_in, const int* in_sizes, int n_in,
                              void* d_out, int out_size, void* d_ws, size_t ws_size,
                              hipStream_t stream) {
    const float* x     = (const float*)d_in[0];
    const float* Wqkv  = (const float*)d_in[1];
    const float* bqkv  = (const float*)d_in[2];
    const float* Ek    = (const float*)d_in[3];
    const float* Ev    = (const float*)d_in[4];
    const float* kbank = (const float*)d_in[5];
    const float* vbank = (const float*)d_in[6];
    const float* Wproj = (const float*)d_in[7];
    const float* bproj = (const float*)d_in[8];
    float* outp        = (float*)d_out;
    short* wsp         = (short*)d_ws;
    (void)in_sizes; (void)n_in; (void)out_size; (void)ws_size;

    hipFuncSetAttribute((const void*)eswa_main,
                        hipFuncAttributeMaxDynamicSharedMemorySize, SMEM_BYTES);

    eswa_prep<<<1040, 256, 0, stream>>>(Wqkv, Wproj, Ek, Ev, wsp);
    eswa_main<<<1024, 512, SMEM_BYTES, stream>>>(x, bqkv, kbank, vbank, bproj,
                                                 wsp, outp);
}

// Round 4
// 264.634 us; speedup vs baseline: 4.4104x; 1.8601x over previous
//
#include <hip/hip_runtime.h>

// B=16, N=4096, C=256, WS=8 -> 1024 windows x 64 tokens; NH=8, HD=32, LK=32, G=16.
// fp32 in/out. MFMA 16x16x32 bf16 everywhere.
// R4 structure: block = window (512 thr, 8 waves).
//   phase 1: QKV for ALL heads (waves split 48 n-tiles; W as bf16 hi+lo from ws)
//   phase 2: wave w = head w, barrier-free: compression -> scores -> register
//            softmax (shfl) -> PV (2 m-halves through a small LDS P buffer)
//   phase 3: proj (waves split 16 n-tiles, no duplicated weight reads)
// 3 barriers total (vs 42 in R3).

typedef unsigned int uint;
typedef __attribute__((ext_vector_type(8))) short short8;   // 8 x bf16
typedef __attribute__((ext_vector_type(4))) float f32x4;

__device__ __forceinline__ float bup(unsigned short hs) {
    return __uint_as_float(((uint)hs) << 16);
}
__device__ __forceinline__ uint f2b(float f) {   // fp32 -> bf16 bits (RNE)
    uint u = __float_as_uint(f);
    return (u + 0x7FFFu + ((u >> 16) & 1u)) >> 16;
}
__device__ __forceinline__ f32x4 mfma16(short8 a, short8 b, f32x4 c) {
    return __builtin_amdgcn_mfma_f32_16x16x32_bf16(a, b, c, 0, 0, 0);
}

// ---- workspace layout (shorts) ----
#define WS_WHQ 0          // [48 tn][8 tk][64 lane][8]  = 196608
#define WS_WLQ 196608
#define WS_WHP 393216     // [16 tn][8 tk][64 lane][8]  = 65536
#define WS_WLP 458752
#define WS_EKT 524288     // [2 tm][2 tk][64 lane][8]   = 2048
#define WS_EVT 526336     // total 528384 shorts = 1056768 B

__global__ void __launch_bounds__(256)
eswa_prep(const float* __restrict__ Wqkv, const float* __restrict__ Wproj,
          const float* __restrict__ Ek, const float* __restrict__ Ev,
          short* __restrict__ wsp)
{
    const int blk = blockIdx.x, thr = threadIdx.x;
    if (blk < 96) {                       // Wqkv: 48 tn x 8 tk x 64 lane
        const int g = blk * 256 + thr;
        const int lane = g & 63, tk = (g >> 6) & 7, tn = g >> 9;
        const int quad = lane >> 4, l16 = lane & 15;
        short8 hi, lo;
        #pragma unroll
        for (int j = 0; j < 8; ++j) {
            const int r = tk * 32 + quad * 8 + j;
            const int c = tn * 16 + l16;
            const float w = Wqkv[r * 768 + c];
            const uint h = f2b(w);
            hi[j] = (short)h;
            lo[j] = (short)f2b(w - bup((unsigned short)h));
        }
        const int o = ((tn * 8 + tk) * 64 + lane) * 8;
        *(short8*)(wsp + WS_WHQ + o) = hi;
        *(short8*)(wsp + WS_WLQ + o) = lo;
    } else if (blk < 128) {               // Wproj: 16 tn x 8 tk x 64 lane
        const int g = (blk - 96) * 256 + thr;
        const int lane = g & 63, tk = (g >> 6) & 7, tn = g >> 9;
        const int quad = lane >> 4, l16 = lane & 15;
        short8 hi, lo;
        #pragma unroll
        for (int j = 0; j < 8; ++j) {
            const int r = tk * 32 + quad * 8 + j;
            const int c = tn * 16 + l16;
            const float w = Wproj[r * 256 + c];
            const uint h = f2b(w);
            hi[j] = (short)h;
            lo[j] = (short)f2b(w - bup((unsigned short)h));
        }
        const int o = ((tn * 8 + tk) * 64 + lane) * 8;
        *(short8*)(wsp + WS_WHP + o) = hi;
        *(short8*)(wsp + WS_WLP + o) = lo;
    } else {                              // Ek (blk 128) / Ev (blk 129)
        const float* E = (blk == 128) ? Ek : Ev;
        const int base = (blk == 128) ? WS_EKT : WS_EVT;
        const int lane = thr & 63, tk = (thr >> 6) & 1, tm = (thr >> 7) & 1;
        const int quad = lane >> 4, l16 = lane & 15;
        short8 v;
        #pragma unroll
        for (int j = 0; j < 8; ++j) {
            const int t = tk * 32 + quad * 8 + j;
            const int lk = tm * 16 + l16;
            v[j] = (short)f2b(E[t * 32 + lk]);
        }
        *(short8*)(wsp + base + ((tm * 2 + tk) * 64 + lane) * 8) = v;
    }
}

// ---- LDS layout (bytes), total 148480 ----
// xh   bf16 [64][264] @ 0           33792   (dead after QKV; attn[8][64][32]
//                                            = 32768 overlays it after barrier 2)
// arena[h] @ 33792 + h*14336, per head 14336:
//   qs   [64][40] @ +0     (5120)  -> overlaid by P [32][72] (4608) after scores
//   kT   [32][72] @ +5120  (4608)  -> overlaid by kfull [48][40] (3840)
//   vT   [32][72] @ +9728  (4608)  -> overlaid in-place by vfullT [32][72]
#define SMEM_BYTES 148480

__global__ void __launch_bounds__(512)
eswa_main(const float* __restrict__ x, const float* __restrict__ bqkv,
          const float* __restrict__ kbank, const float* __restrict__ vbank,
          const float* __restrict__ bproj, const short* __restrict__ wsp,
          float* __restrict__ out)
{
    extern __shared__ char smem[];
    short* xh = (short*)smem;                     // [64][264]

    const int tid  = threadIdx.x;
    const int wave = tid >> 6;
    const int lane = tid & 63;
    const int quad = lane >> 4;
    const int l16  = lane & 15;

    const int b  = blockIdx.x >> 6;
    const int w  = blockIdx.x & 63;
    const int rw = w >> 3;
    const int cw = w & 7;

    // ================= stage: x -> bf16 LDS [token][264] =================
    #pragma unroll
    for (int i = 0; i < 8; ++i) {
        const int vi = tid + 512 * i;             // 0..4095
        const int t  = vi >> 6;
        const int c  = (vi & 63) * 4;
        const int n  = (rw * 8 + (t >> 3)) * 64 + cw * 8 + (t & 7);
        const float4 xv = *(const float4*)(x + (size_t)(b * 4096 + n) * 256 + c);
        const uint h0 = f2b(xv.x), h1 = f2b(xv.y), h2 = f2b(xv.z), h3 = f2b(xv.w);
        *(uint2*)(xh + t * 264 + c) = make_uint2(h0 | (h1 << 16), h2 | (h3 << 16));
    }
    __syncthreads();   // barrier 1

    // ================= phase 1: QKV all heads =================
    // wave w owns n-tiles w*6 .. w*6+5 (two groups of 3), all 4 m-tiles.
    {
        const short* Whq = wsp + WS_WHQ;
        const short* Wlq = wsp + WS_WLQ;
        #pragma unroll 1
        for (int gi = 0; gi < 2; ++gi) {
            const int tnb = wave * 6 + gi * 3;
            f32x4 acc[3][4];
            #pragma unroll
            for (int p = 0; p < 3; ++p) {
                const int tn = tnb + p;
                const int sec = tn >> 4, hh = (tn >> 1) & 7, half = tn & 1;
                const float bv = bqkv[sec * 256 + hh * 32 + half * 16 + l16];
                #pragma unroll
                for (int m = 0; m < 4; ++m) acc[p][m] = (f32x4){bv, bv, bv, bv};
            }
            #pragma unroll 2
            for (int tk = 0; tk < 8; ++tk) {
                short8 af[4];
                #pragma unroll
                for (int m = 0; m < 4; ++m)
                    af[m] = *(const short8*)(xh + (m * 16 + l16) * 264 + tk * 32 + quad * 8);
                #pragma unroll
                for (int p = 0; p < 3; ++p) {
                    const int bo = (((tnb + p) * 8 + tk) * 64 + lane) * 8;
                    const short8 bh = *(const short8*)(Whq + bo);
                    const short8 bl = *(const short8*)(Wlq + bo);
                    #pragma unroll
                    for (int m = 0; m < 4; ++m) {
                        acc[p][m] = mfma16(af[m], bh, acc[p][m]);
                        acc[p][m] = mfma16(af[m], bl, acc[p][m]);
                    }
                }
            }
            // epilogue: scatter to per-head arenas (q scaled by 1/sqrt(hd))
            #pragma unroll
            for (int p = 0; p < 3; ++p) {
                const int tn = tnb + p;
                const int sec = tn >> 4, hh = (tn >> 1) & 7, half = tn & 1;
                short* arena = (short*)(smem + 33792 + hh * 14336);
                #pragma unroll
                for (int m = 0; m < 4; ++m) {
                    #pragma unroll
                    for (int r = 0; r < 4; ++r) {
                        const int t = m * 16 + quad * 4 + r;
                        const float v = acc[p][m][r];
                        if (sec == 0)
                            arena[t * 40 + half * 16 + l16] =
                                (short)f2b(v * 0.17677669529663687f);
                        else if (sec == 1)
                            (arena + 2560)[(half * 16 + l16) * 72 + t] = (short)f2b(v);
                        else
                            (arena + 4864)[(half * 16 + l16) * 72 + t] = (short)f2b(v);
                    }
                }
            }
        }
    }
    __syncthreads();   // barrier 2

    // ========== phase 2: per-head attention, wave-local, NO barriers ==========
    {
        const int h = wave;
        short* arena = (short*)(smem + 33792 + h * 14336);
        short* qsb = arena;            // [64][40] -> P [32][72] later
        short* kTb = arena + 2560;     // [32][72] -> kfull [48][40]
        short* vTb = arena + 4864;     // [32][72] -> vfullT [32][72]

        // --- 2a: Linformer compression ---
        short8 kB[2][2], vB[2][2];     // raw k/v B-frags (loaded before overwrite)
        #pragma unroll
        for (int tn = 0; tn < 2; ++tn)
            #pragma unroll
            for (int tk = 0; tk < 2; ++tk) {
                kB[tn][tk] = *(const short8*)(kTb + (tn * 16 + l16) * 72 + tk * 32 + quad * 8);
                vB[tn][tk] = *(const short8*)(vTb + (tn * 16 + l16) * 72 + tk * 32 + quad * 8);
            }
        f32x4 kc[2][2], vc[2][2];
        #pragma unroll
        for (int tm = 0; tm < 2; ++tm)
            #pragma unroll
            for (int tn = 0; tn < 2; ++tn) {
                kc[tm][tn] = (f32x4){0.f, 0.f, 0.f, 0.f};
                vc[tm][tn] = (f32x4){0.f, 0.f, 0.f, 0.f};
            }
        #pragma unroll
        for (int tm = 0; tm < 2; ++tm)
            #pragma unroll
            for (int tk = 0; tk < 2; ++tk) {
                const short8 ak = *(const short8*)(wsp + WS_EKT + ((tm * 2 + tk) * 64 + lane) * 8);
                const short8 av = *(const short8*)(wsp + WS_EVT + ((tm * 2 + tk) * 64 + lane) * 8);
                #pragma unroll
                for (int tn = 0; tn < 2; ++tn) {
                    kc[tm][tn] = mfma16(ak, kB[tn][tk], kc[tm][tn]);
                    vc[tm][tn] = mfma16(av, vB[tn][tk], vc[tm][tn]);
                }
            }
        // overwrite kT with kfull, vT with vfullT (in-wave DS order is safe)
        #pragma unroll
        for (int tm = 0; tm < 2; ++tm)
            #pragma unroll
            for (int tn = 0; tn < 2; ++tn)
                #pragma unroll
                for (int r = 0; r < 4; ++r) {
                    const int lk = tm * 16 + quad * 4 + r;
                    const int d  = tn * 16 + l16;
                    kTb[lk * 40 + d] = (short)f2b(kc[tm][tn][r]);
                    vTb[d * 72 + lk] = (short)f2b(vc[tm][tn][r]);
                }
        // bank rows 32..47
        {
            const int g = lane >> 2, dq = (lane & 3) * 8;
            const float4 k0 = *(const float4*)(kbank + g * 256 + h * 32 + dq);
            const float4 k1 = *(const float4*)(kbank + g * 256 + h * 32 + dq + 4);
            *(uint4*)(kTb + (32 + g) * 40 + dq) = make_uint4(
                f2b(k0.x) | (f2b(k0.y) << 16), f2b(k0.z) | (f2b(k0.w) << 16),
                f2b(k1.x) | (f2b(k1.y) << 16), f2b(k1.z) | (f2b(k1.w) << 16));
            const float4 v0 = *(const float4*)(vbank + g * 256 + h * 32 + dq);
            const float4 v1 = *(const float4*)(vbank + g * 256 + h * 32 + dq + 4);
            vTb[(dq + 0) * 72 + 32 + g] = (short)f2b(v0.x);
            vTb[(dq + 1) * 72 + 32 + g] = (short)f2b(v0.y);
            vTb[(dq + 2) * 72 + 32 + g] = (short)f2b(v0.z);
            vTb[(dq + 3) * 72 + 32 + g] = (short)f2b(v0.w);
            vTb[(dq + 4) * 72 + 32 + g] = (short)f2b(v1.x);
            vTb[(dq + 5) * 72 + 32 + g] = (short)f2b(v1.y);
            vTb[(dq + 6) * 72 + 32 + g] = (short)f2b(v1.z);
            vTb[(dq + 7) * 72 + 32 + g] = (short)f2b(v1.w);
        }
        // zero vfullT key-cols 48..63 (PV K-pad)
        *(uint4*)(vTb + (lane >> 1) * 72 + 48 + (lane & 1) * 8) = make_uint4(0, 0, 0, 0);

        // --- 2b: scores (q pre-scaled) ---
        short8 qA[4];
        #pragma unroll
        for (int m = 0; m < 4; ++m)
            qA[m] = *(const short8*)(qsb + (m * 16 + l16) * 40 + quad * 8);
        short8 kfB[3];
        #pragma unroll
        for (int n = 0; n < 3; ++n)
            kfB[n] = *(const short8*)(kTb + (n * 16 + l16) * 40 + quad * 8);
        f32x4 sc[4][3];
        #pragma unroll
        for (int m = 0; m < 4; ++m)
            #pragma unroll
            for (int n = 0; n < 3; ++n) {
                sc[m][n] = (f32x4){0.f, 0.f, 0.f, 0.f};
                sc[m][n] = mfma16(qA[m], kfB[n], sc[m][n]);
            }

        // --- 2c: softmax in registers (reduce across l16 via shfl) ---
        f32x4 inv4[4];
        #pragma unroll
        for (int m = 0; m < 4; ++m) {
            #pragma unroll
            for (int r = 0; r < 4; ++r) {
                float mm = fmaxf(fmaxf(sc[m][0][r], sc[m][1][r]), sc[m][2][r]);
                mm = fmaxf(mm, __shfl_xor(mm, 1));
                mm = fmaxf(mm, __shfl_xor(mm, 2));
                mm = fmaxf(mm, __shfl_xor(mm, 4));
                mm = fmaxf(mm, __shfl_xor(mm, 8));
                const float e0 = __expf(sc[m][0][r] - mm);
                const float e1 = __expf(sc[m][1][r] - mm);
                const float e2 = __expf(sc[m][2][r] - mm);
                sc[m][0][r] = e0; sc[m][1][r] = e1; sc[m][2][r] = e2;
                float s = e0 + e1 + e2;
                s += __shfl_xor(s, 1);
                s += __shfl_xor(s, 2);
                s += __shfl_xor(s, 4);
                s += __shfl_xor(s, 8);
                inv4[m][r] = 1.0f / s;
            }
        }

        // --- 2d: PV in two 32-row halves through P buffer (overlays qs) ---
        short* Pb = qsb;   // [32][72], 4608 B <= 5120 B
        *(uint4*)(Pb + (lane >> 1) * 72 + 48 + (lane & 1) * 8) = make_uint4(0, 0, 0, 0);
        short8 vfB[2][2];
        #pragma unroll
        for (int tn = 0; tn < 2; ++tn)
            #pragma unroll
            for (int tk = 0; tk < 2; ++tk)
                vfB[tn][tk] = *(const short8*)(vTb + (tn * 16 + l16) * 72 + tk * 32 + quad * 8);

        #pragma unroll
        for (int half = 0; half < 2; ++half) {
            #pragma unroll
            for (int ml = 0; ml < 2; ++ml) {
                const int m = half * 2 + ml;
                #pragma unroll
                for (int n = 0; n < 3; ++n)
                    #pragma unroll
                    for (int r = 0; r < 4; ++r)
                        Pb[(ml * 16 + quad * 4 + r) * 72 + n * 16 + l16] =
                            (short)f2b(sc[m][n][r] * inv4[m][r]);
            }
            short8 pA[2][2];
            #pragma unroll
            for (int ml = 0; ml < 2; ++ml)
                #pragma unroll
                for (int tk = 0; tk < 2; ++tk)
                    pA[ml][tk] = *(const short8*)(Pb + (ml * 16 + l16) * 72 + tk * 32 + quad * 8);
            f32x4 oa[2][2];
            #pragma unroll
            for (int ml = 0; ml < 2; ++ml)
                #pragma unroll
                for (int tn = 0; tn < 2; ++tn) {
                    oa[ml][tn] = (f32x4){0.f, 0.f, 0.f, 0.f};
                    oa[ml][tn] = mfma16(pA[ml][0], vfB[tn][0], oa[ml][tn]);
                    oa[ml][tn] = mfma16(pA[ml][1], vfB[tn][1], oa[ml][tn]);
                }
            // attn overlay on xh: attn[h][64][32] shorts, base h*2048
            #pragma unroll
            for (int ml = 0; ml < 2; ++ml)
                #pragma unroll
                for (int tn = 0; tn < 2; ++tn)
                    #pragma unroll
                    for (int r = 0; r < 4; ++r) {
                        const int t = half * 32 + ml * 16 + quad * 4 + r;
                        ((short*)smem)[h * 2048 + t * 32 + tn * 16 + l16] =
                            (short)f2b(oa[ml][tn][r]);
                    }
        }
    }
    __syncthreads();   // barrier 3

    // ================= phase 3: output projection =================
    // wave w: n-tiles w*2, w*2+1 (no duplicated weight reads), all 4 m-tiles.
    {
        const short* Whp = wsp + WS_WHP;
        const short* Wlp = wsp + WS_WLP;
        const short* attnS = (const short*)smem;
        f32x4 acc[2][4];
        #pragma unroll
        for (int tnl = 0; tnl < 2; ++tnl) {
            const float bi = bproj[(wave * 2 + tnl) * 16 + l16];
            #pragma unroll
            for (int m = 0; m < 4; ++m) acc[tnl][m] = (f32x4){bi, bi, bi, bi};
        }
        #pragma unroll 2
        for (int tk = 0; tk < 8; ++tk) {
            short8 aA[4];
            #pragma unroll
            for (int m = 0; m < 4; ++m)
                aA[m] = *(const short8*)(attnS + tk * 2048 + (m * 16 + l16) * 32 + quad * 8);
            #pragma unroll
            for (int tnl = 0; tnl < 2; ++tnl) {
                const int bo = (((wave * 2 + tnl) * 8 + tk) * 64 + lane) * 8;
                const short8 bh = *(const short8*)(Whp + bo);
                const short8 bl = *(const short8*)(Wlp + bo);
                #pragma unroll
                for (int m = 0; m < 4; ++m) {
                    acc[tnl][m] = mfma16(aA[m], bh, acc[tnl][m]);
                    acc[tnl][m] = mfma16(aA[m], bl, acc[tnl][m]);
                }
            }
        }
        #pragma unroll
        for (int tnl = 0; tnl < 2; ++tnl)
            #pragma unroll
            for (int m = 0; m < 4; ++m)
                #pragma unroll
                for (int r = 0; r < 4; ++r) {
                    const int t = m * 16 + quad * 4 + r;
                    const int n = (rw * 8 + (t >> 3)) * 64 + cw * 8 + (t & 7);
                    out[(size_t)(b * 4096 + n) * 256 + (wave * 2 + tnl) * 16 + l16] =
                        acc[tnl][m][r];
                }
    }
}

extern "C" void kernel_launch(void* const* d_in, const int* in_sizes, int n_in,
                              void* d_out, int out_size, void* d_ws, size_t ws_size,
                              hipStream_t stream) {
    const float* x     = (const float*)d_in[0];
    const float* Wqkv  = (const float*)d_in[1];
    const float* bqkv  = (const float*)d_in[2];
    const float* Ek    = (const float*)d_in[3];
    const float* Ev    = (const float*)d_in[4];
    const float* kbank = (const float*)d_in[5];
    const float* vbank = (const float*)d_in[6];
    const float* Wproj = (const float*)d_in[7];
    const float* bproj = (const float*)d_in[8];
    float* outp        = (float*)d_out;
    short* wsp         = (short*)d_ws;
    (void)in_sizes; (void)n_in; (void)out_size; (void)ws_size;

    hipFuncSetAttribute((const void*)eswa_main,
                        hipFuncAttributeMaxDynamicSharedMemorySize, SMEM_BYTES);

    eswa_prep<<<130, 256, 0, stream>>>(Wqkv, Wproj, Ek, Ev, wsp);
    eswa_main<<<1024, 512, SMEM_BYTES, stream>>>(x, bqkv, kbank, vbank, bproj,
                                                 wsp, outp);
}

// Round 5
// 207.592 us; speedup vs baseline: 5.6223x; 1.2748x over previous
//
#include <hip/hip_runtime.h>

// B=16, N=4096, C=256, WS=8 -> 1024 windows x 64 tokens; NH=8, HD=32, LK=32, G=16.
// fp32 in/out. MFMA 16x16x32 bf16.
// R5: block = window, 1024 threads (16 waves, 4 waves/SIMD at 1 block/CU).
//   QKV uses W-hi only (bf16): q/k/v are bf16-rounded at output anyway, so
//   the extra error is second-order. Proj keeps hi+lo.
//   Phase 2: wave pair (2h+s) owns head h, split by m/tm half s.
//   6 block barriers total.

typedef unsigned int uint;
typedef __attribute__((ext_vector_type(8))) short short8;   // 8 x bf16
typedef __attribute__((ext_vector_type(4))) float f32x4;

__device__ __forceinline__ float bup(unsigned short hs) {
    return __uint_as_float(((uint)hs) << 16);
}
__device__ __forceinline__ uint f2b(float f) {   // fp32 -> bf16 bits (RNE)
    uint u = __float_as_uint(f);
    return (u + 0x7FFFu + ((u >> 16) & 1u)) >> 16;
}
__device__ __forceinline__ f32x4 mfma16(short8 a, short8 b, f32x4 c) {
    return __builtin_amdgcn_mfma_f32_16x16x32_bf16(a, b, c, 0, 0, 0);
}

// ---- workspace layout (shorts) ----
#define WS_WHQ 0          // [48 tn][8 tk][64 lane][8]  = 196608 (hi only)
#define WS_WHP 196608     // [16 tn][8 tk][64 lane][8]  = 65536
#define WS_WLP 262144     // 65536
#define WS_EKT 327680     // [2 tm][2 tk][64 lane][8]   = 2048
#define WS_EVT 329728     // total 331776 shorts = 663552 B

__global__ void __launch_bounds__(256)
eswa_prep(const float* __restrict__ Wqkv, const float* __restrict__ Wproj,
          const float* __restrict__ Ek, const float* __restrict__ Ev,
          short* __restrict__ wsp)
{
    const int blk = blockIdx.x, thr = threadIdx.x;
    if (blk < 96) {                       // Wqkv hi: 48 tn x 8 tk x 64 lane
        const int g = blk * 256 + thr;
        const int lane = g & 63, tk = (g >> 6) & 7, tn = g >> 9;
        const int quad = lane >> 4, l16 = lane & 15;
        short8 hi;
        #pragma unroll
        for (int j = 0; j < 8; ++j) {
            const int r = tk * 32 + quad * 8 + j;
            const int c = tn * 16 + l16;
            hi[j] = (short)f2b(Wqkv[r * 768 + c]);
        }
        *(short8*)(wsp + WS_WHQ + ((tn * 8 + tk) * 64 + lane) * 8) = hi;
    } else if (blk < 128) {               // Wproj hi+lo: 16 tn x 8 tk x 64 lane
        const int g = (blk - 96) * 256 + thr;
        const int lane = g & 63, tk = (g >> 6) & 7, tn = g >> 9;
        const int quad = lane >> 4, l16 = lane & 15;
        short8 hi, lo;
        #pragma unroll
        for (int j = 0; j < 8; ++j) {
            const int r = tk * 32 + quad * 8 + j;
            const int c = tn * 16 + l16;
            const float w = Wproj[r * 256 + c];
            const uint h = f2b(w);
            hi[j] = (short)h;
            lo[j] = (short)f2b(w - bup((unsigned short)h));
        }
        const int o = ((tn * 8 + tk) * 64 + lane) * 8;
        *(short8*)(wsp + WS_WHP + o) = hi;
        *(short8*)(wsp + WS_WLP + o) = lo;
    } else {                              // Ek (blk 128) / Ev (blk 129)
        const float* E = (blk == 128) ? Ek : Ev;
        const int base = (blk == 128) ? WS_EKT : WS_EVT;
        const int lane = thr & 63, tk = (thr >> 6) & 1, tm = (thr >> 7) & 1;
        const int quad = lane >> 4, l16 = lane & 15;
        short8 v;
        #pragma unroll
        for (int j = 0; j < 8; ++j) {
            const int t = tk * 32 + quad * 8 + j;
            const int lk = tm * 16 + l16;
            v[j] = (short)f2b(E[t * 32 + lk]);
        }
        *(short8*)(wsp + base + ((tm * 2 + tk) * 64 + lane) * 8) = v;
    }
}

// ---- LDS layout (bytes), total 148480 ----
// xh   bf16 [64][264] @ 0        33792  (dead after QKV; attn[8][64][32]=32768
//                                        overlays it after barrier 2)
// arena[h] @ 33792 + h*14336, per head 14336:
//   qs [64][40] @ +0    (5120)  -> P(s=0) [32][72] (4608) after softmax
//   kT [32][72] @ +5120 (4608)  -> kfull [48][40] (3840) / P(s=1) after softmax
//   vT [32][72] @ +9728 (4608)  -> vfullT [32][72] in place
#define SMEM_BYTES 148480

__global__ void __launch_bounds__(1024, 4)
eswa_main(const float* __restrict__ x, const float* __restrict__ bqkv,
          const float* __restrict__ kbank, const float* __restrict__ vbank,
          const float* __restrict__ bproj, const short* __restrict__ wsp,
          float* __restrict__ out)
{
    extern __shared__ char smem[];
    short* xh = (short*)smem;                     // [64][264]

    const int tid  = threadIdx.x;
    const int wave = tid >> 6;                    // 0..15
    const int lane = tid & 63;
    const int quad = lane >> 4;
    const int l16  = lane & 15;

    const int b  = blockIdx.x >> 6;
    const int w  = blockIdx.x & 63;
    const int rw = w >> 3;
    const int cw = w & 7;

    // ================= stage: x -> bf16 LDS [token][264] =================
    #pragma unroll
    for (int i = 0; i < 4; ++i) {
        const int vi = tid + 1024 * i;            // 0..4095
        const int t  = vi >> 6;
        const int c  = (vi & 63) * 4;
        const int n  = (rw * 8 + (t >> 3)) * 64 + cw * 8 + (t & 7);
        const float4 xv = *(const float4*)(x + (size_t)(b * 4096 + n) * 256 + c);
        const uint h0 = f2b(xv.x), h1 = f2b(xv.y), h2 = f2b(xv.z), h3 = f2b(xv.w);
        *(uint2*)(xh + t * 264 + c) = make_uint2(h0 | (h1 << 16), h2 | (h3 << 16));
    }
    __syncthreads();   // B1

    // ================= phase 1: QKV all heads (W-hi only) =================
    // wave w owns n-tiles w*3 .. w*3+2, all 4 m-tiles.
    {
        const short* Whq = wsp + WS_WHQ;
        const int tn0 = wave * 3;
        f32x4 acc[3][4];
        #pragma unroll
        for (int p = 0; p < 3; ++p) {
            const int tn = tn0 + p;
            const int sec = tn >> 4, hh = (tn >> 1) & 7, half = tn & 1;
            const float bv = bqkv[sec * 256 + hh * 32 + half * 16 + l16];
            #pragma unroll
            for (int m = 0; m < 4; ++m) acc[p][m] = (f32x4){bv, bv, bv, bv};
        }
        #pragma unroll 2
        for (int tk = 0; tk < 8; ++tk) {
            short8 af[4];
            #pragma unroll
            for (int m = 0; m < 4; ++m)
                af[m] = *(const short8*)(xh + (m * 16 + l16) * 264 + tk * 32 + quad * 8);
            #pragma unroll
            for (int p = 0; p < 3; ++p) {
                const short8 bh = *(const short8*)(Whq + (((tn0 + p) * 8 + tk) * 64 + lane) * 8);
                #pragma unroll
                for (int m = 0; m < 4; ++m)
                    acc[p][m] = mfma16(af[m], bh, acc[p][m]);
            }
        }
        // epilogue: scatter to per-head arenas (q pre-scaled by 1/sqrt(hd))
        #pragma unroll
        for (int p = 0; p < 3; ++p) {
            const int tn = tn0 + p;
            const int sec = tn >> 4, hh = (tn >> 1) & 7, half = tn & 1;
            short* arena = (short*)(smem + 33792 + hh * 14336);
            #pragma unroll
            for (int m = 0; m < 4; ++m) {
                #pragma unroll
                for (int r = 0; r < 4; ++r) {
                    const int t = m * 16 + quad * 4 + r;
                    const float v = acc[p][m][r];
                    if (sec == 0)
                        arena[t * 40 + half * 16 + l16] =
                            (short)f2b(v * 0.17677669529663687f);
                    else if (sec == 1)
                        (arena + 2560)[(half * 16 + l16) * 72 + t] = (short)f2b(v);
                    else
                        (arena + 4864)[(half * 16 + l16) * 72 + t] = (short)f2b(v);
                }
            }
        }
    }
    __syncthreads();   // B2

    // ====== phase 2: head h = wave>>1, half s = wave&1 ======
    const int h = wave >> 1, s = wave & 1;
    short* arena = (short*)(smem + 33792 + h * 14336);
    short* qsb = arena;            // [64][40]
    short* kTb = arena + 2560;     // [32][72] -> kfull [48][40]
    short* vTb = arena + 4864;     // [32][72] -> vfullT [32][72]
    const int gB  = s * 8 + (lane >> 3);     // bank row 0..15
    const int dqB = (lane & 7) * 4;          // bank d-offset

    // --- 2a-load: raw k/v B-frags + E-frags + bank values (before overwrite) ---
    short8 kB[2][2], vB[2][2];
    #pragma unroll
    for (int tn = 0; tn < 2; ++tn)
        #pragma unroll
        for (int tk = 0; tk < 2; ++tk) {
            kB[tn][tk] = *(const short8*)(kTb + (tn * 16 + l16) * 72 + tk * 32 + quad * 8);
            vB[tn][tk] = *(const short8*)(vTb + (tn * 16 + l16) * 72 + tk * 32 + quad * 8);
        }
    short8 akE[2], avE[2];
    #pragma unroll
    for (int tk = 0; tk < 2; ++tk) {
        akE[tk] = *(const short8*)(wsp + WS_EKT + ((s * 2 + tk) * 64 + lane) * 8);
        avE[tk] = *(const short8*)(wsp + WS_EVT + ((s * 2 + tk) * 64 + lane) * 8);
    }
    const float4 kbv = *(const float4*)(kbank + gB * 256 + h * 32 + dqB);
    const float4 vbv = *(const float4*)(vbank + gB * 256 + h * 32 + dqB);
    __syncthreads();   // B3: all raw-frag loads done before overwrites

    // --- 2a-compute: compression (this wave: tm = s) + bank fill + pads ---
    {
        f32x4 kc[2], vc[2];
        #pragma unroll
        for (int tn = 0; tn < 2; ++tn) { kc[tn] = (f32x4){0,0,0,0}; vc[tn] = (f32x4){0,0,0,0}; }
        #pragma unroll
        for (int tk = 0; tk < 2; ++tk)
            #pragma unroll
            for (int tn = 0; tn < 2; ++tn) {
                kc[tn] = mfma16(akE[tk], kB[tn][tk], kc[tn]);
                vc[tn] = mfma16(avE[tk], vB[tn][tk], vc[tn]);
            }
        #pragma unroll
        for (int tn = 0; tn < 2; ++tn)
            #pragma unroll
            for (int r = 0; r < 4; ++r) {
                const int lk = s * 16 + quad * 4 + r;
                const int d  = tn * 16 + l16;
                kTb[lk * 40 + d] = (short)f2b(kc[tn][r]);
                vTb[d * 72 + lk] = (short)f2b(vc[tn][r]);
            }
        // bank rows 32..47
        kTb[(32 + gB) * 40 + dqB + 0] = (short)f2b(kbv.x);
        kTb[(32 + gB) * 40 + dqB + 1] = (short)f2b(kbv.y);
        kTb[(32 + gB) * 40 + dqB + 2] = (short)f2b(kbv.z);
        kTb[(32 + gB) * 40 + dqB + 3] = (short)f2b(kbv.w);
        vTb[(dqB + 0) * 72 + 32 + gB] = (short)f2b(vbv.x);
        vTb[(dqB + 1) * 72 + 32 + gB] = (short)f2b(vbv.y);
        vTb[(dqB + 2) * 72 + 32 + gB] = (short)f2b(vbv.z);
        vTb[(dqB + 3) * 72 + 32 + gB] = (short)f2b(vbv.w);
        // zero vfullT key-cols 48..63 (PV K-pad), one wave of the pair
        if (s == 0)
            *(uint4*)(vTb + (lane >> 1) * 72 + 48 + (lane & 1) * 8) = make_uint4(0, 0, 0, 0);
    }
    __syncthreads();   // B4: kfull/vfullT complete

    // --- 2b: scores for m-tiles {2s, 2s+1} (q pre-scaled) ---
    f32x4 sc[2][3];
    f32x4 inv4[2];
    {
        short8 qA[2], kfB[3];
        #pragma unroll
        for (int ml = 0; ml < 2; ++ml)
            qA[ml] = *(const short8*)(qsb + ((2 * s + ml) * 16 + l16) * 40 + quad * 8);
        #pragma unroll
        for (int n = 0; n < 3; ++n)
            kfB[n] = *(const short8*)(kTb + (n * 16 + l16) * 40 + quad * 8);
        #pragma unroll
        for (int ml = 0; ml < 2; ++ml)
            #pragma unroll
            for (int n = 0; n < 3; ++n) {
                sc[ml][n] = (f32x4){0, 0, 0, 0};
                sc[ml][n] = mfma16(qA[ml], kfB[n], sc[ml][n]);
            }
        // --- 2c: softmax in registers (reduce across l16 via shfl) ---
        #pragma unroll
        for (int ml = 0; ml < 2; ++ml) {
            #pragma unroll
            for (int r = 0; r < 4; ++r) {
                float mm = fmaxf(fmaxf(sc[ml][0][r], sc[ml][1][r]), sc[ml][2][r]);
                mm = fmaxf(mm, __shfl_xor(mm, 1));
                mm = fmaxf(mm, __shfl_xor(mm, 2));
                mm = fmaxf(mm, __shfl_xor(mm, 4));
                mm = fmaxf(mm, __shfl_xor(mm, 8));
                const float e0 = __expf(sc[ml][0][r] - mm);
                const float e1 = __expf(sc[ml][1][r] - mm);
                const float e2 = __expf(sc[ml][2][r] - mm);
                sc[ml][0][r] = e0; sc[ml][1][r] = e1; sc[ml][2][r] = e2;
                float su = e0 + e1 + e2;
                su += __shfl_xor(su, 1);
                su += __shfl_xor(su, 2);
                su += __shfl_xor(su, 4);
                su += __shfl_xor(su, 8);
                inv4[ml][r] = 1.0f / su;
            }
        }
    }
    __syncthreads();   // B5: kfull dead, safe to overwrite with P

    // --- 2d: PV for this wave's 32 tokens ---
    {
        short* Pb = (s == 0) ? qsb : kTb;      // [32][72]
        #pragma unroll
        for (int ml = 0; ml < 2; ++ml)
            #pragma unroll
            for (int n = 0; n < 3; ++n)
                #pragma unroll
                for (int r = 0; r < 4; ++r)
                    Pb[(ml * 16 + quad * 4 + r) * 72 + n * 16 + l16] =
                        (short)f2b(sc[ml][n][r] * inv4[ml][r]);
        *(uint4*)(Pb + (lane >> 1) * 72 + 48 + (lane & 1) * 8) = make_uint4(0, 0, 0, 0);

        short8 vfB[2][2], pA[2][2];
        #pragma unroll
        for (int tn = 0; tn < 2; ++tn)
            #pragma unroll
            for (int tk = 0; tk < 2; ++tk)
                vfB[tn][tk] = *(const short8*)(vTb + (tn * 16 + l16) * 72 + tk * 32 + quad * 8);
        #pragma unroll
        for (int ml = 0; ml < 2; ++ml)
            #pragma unroll
            for (int tk = 0; tk < 2; ++tk)
                pA[ml][tk] = *(const short8*)(Pb + (ml * 16 + l16) * 72 + tk * 32 + quad * 8);
        #pragma unroll
        for (int ml = 0; ml < 2; ++ml)
            #pragma unroll
            for (int tn = 0; tn < 2; ++tn) {
                f32x4 oa = (f32x4){0, 0, 0, 0};
                oa = mfma16(pA[ml][0], vfB[tn][0], oa);
                oa = mfma16(pA[ml][1], vfB[tn][1], oa);
                #pragma unroll
                for (int r = 0; r < 4; ++r) {
                    const int t = s * 32 + ml * 16 + quad * 4 + r;
                    ((short*)smem)[h * 2048 + t * 32 + tn * 16 + l16] =
                        (short)f2b(oa[r]);
                }
            }
    }
    __syncthreads();   // B6

    // ================= phase 3: output projection =================
    // wave w: n-tile w, all 4 m-tiles; W hi+lo.
    {
        const short* Whp = wsp + WS_WHP;
        const short* Wlp = wsp + WS_WLP;
        const short* attnS = (const short*)smem;   // [tk(8 heads)][64][32]
        const int tn = wave;
        f32x4 acc[4];
        {
            const float bi = bproj[tn * 16 + l16];
            #pragma unroll
            for (int m = 0; m < 4; ++m) acc[m] = (f32x4){bi, bi, bi, bi};
        }
        #pragma unroll 2
        for (int tk = 0; tk < 8; ++tk) {
            short8 aA[4];
            #pragma unroll
            for (int m = 0; m < 4; ++m)
                aA[m] = *(const short8*)(attnS + tk * 2048 + (m * 16 + l16) * 32 + quad * 8);
            const int bo = ((tn * 8 + tk) * 64 + lane) * 8;
            const short8 bh = *(const short8*)(Whp + bo);
            const short8 bl = *(const short8*)(Wlp + bo);
            #pragma unroll
            for (int m = 0; m < 4; ++m) {
                acc[m] = mfma16(aA[m], bh, acc[m]);
                acc[m] = mfma16(aA[m], bl, acc[m]);
            }
        }
        #pragma unroll
        for (int m = 0; m < 4; ++m)
            #pragma unroll
            for (int r = 0; r < 4; ++r) {
                const int t = m * 16 + quad * 4 + r;
                const int n = (rw * 8 + (t >> 3)) * 64 + cw * 8 + (t & 7);
                out[(size_t)(b * 4096 + n) * 256 + tn * 16 + l16] = acc[m][r];
            }
    }
}

extern "C" void kernel_launch(void* const* d_in, const int* in_sizes, int n_in,
                              void* d_out, int out_size, void* d_ws, size_t ws_size,
                              hipStream_t stream) {
    const float* x     = (const float*)d_in[0];
    const float* Wqkv  = (const float*)d_in[1];
    const float* bqkv  = (const float*)d_in[2];
    const float* Ek    = (const float*)d_in[3];
    const float* Ev    = (const float*)d_in[4];
    const float* kbank = (const float*)d_in[5];
    const float* vbank = (const float*)d_in[6];
    const float* Wproj = (const float*)d_in[7];
    const float* bproj = (const float*)d_in[8];
    float* outp        = (float*)d_out;
    short* wsp         = (short*)d_ws;
    (void)in_sizes; (void)n_in; (void)out_size; (void)ws_size;

    hipFuncSetAttribute((const void*)eswa_main,
                        hipFuncAttributeMaxDynamicSharedMemorySize, SMEM_BYTES);

    eswa_prep<<<130, 256, 0, stream>>>(Wqkv, Wproj, Ek, Ev, wsp);
    eswa_main<<<1024, 1024, SMEM_BYTES, stream>>>(x, bqkv, kbank, vbank, bproj,
                                                  wsp, outp);
}